// Round 4
// baseline (471.688 us; speedup 1.0000x reference)
//
#include <hip/hip_runtime.h>
#include <math.h>

#define KF 8
#define LL 8
#define TT (1 << 18)
#define HID 64
#define INF 16          // L*F = MLP input dim
// LDS strides (floats). Bank = float_index % 32.
//   1064 % 32 = 8 -> clusters at bank offsets {0,8,16,24} -> 2-way max (free, m136)
#define W1S 1064
#define BS  72          // 72 % 32 = 8, 72 % 4 = 0
#define BT  256
#define NBUCK 32768     // 8 clusters x 4096 morton cells (res-16 grid)

// ---------- helpers ----------

__device__ __forceinline__ int cluster_assign(float px, float py, float pz,
                                              const float* __restrict__ c) {
    int a = 0; float best = 1e30f;
    #pragma unroll
    for (int k = 0; k < KF; ++k) {
        float dx = px - c[k * 3 + 0];
        float dy = py - c[k * 3 + 1];
        float dz = pz - c[k * 3 + 2];
        float d2 = fmaf(dx, dx, fmaf(dy, dy, dz * dz));
        bool lt = d2 < best;
        a = lt ? k : a;
        best = lt ? d2 : best;
    }
    return a;
}

__device__ __forceinline__ unsigned morton12(float px, float py, float pz) {
    unsigned x = min((unsigned)(int)floorf(px * 16.f), 15u);
    unsigned y = min((unsigned)(int)floorf(py * 16.f), 15u);
    unsigned z = min((unsigned)(int)floorf(pz * 16.f), 15u);
    unsigned m = 0;
    #pragma unroll
    for (int b = 0; b < 4; ++b) {
        m |= ((x >> b) & 1u) << (3 * b);
        m |= ((y >> b) & 1u) << (3 * b + 1);
        m |= ((z >> b) & 1u) << (3 * b + 2);
    }
    return m;
}

__device__ __forceinline__ int sort_key(float px, float py, float pz,
                                        const float* __restrict__ cent) {
    return (cluster_assign(px, py, pz, cent) << 12) | (int)morton12(px, py, pz);
}

// x-paired gather (x-hash prime is 1): even-ix corner pairs live in one float4.
__device__ __forceinline__ float2 gather_level(const float2* __restrict__ tl,
                                               float px, float py, float pz, int l) {
    const float res = (float)(16 << l);
    const float sx = px * res, sy = py * res, sz = pz * res;
    const float fx = floorf(sx), fy = floorf(sy), fz = floorf(sz);
    const float wx = sx - fx, wy = sy - fy, wz = sz - fz;
    const unsigned ix = (unsigned)(int)fx;
    const unsigned iy = (unsigned)(int)fy;
    const unsigned iz = (unsigned)(int)fz;
    const unsigned M = TT - 1;

    const unsigned hy0 = iy * 2654435761u;
    const unsigned hy1 = (iy + 1u) * 2654435761u;
    const unsigned hz0 = iz * 805459861u;
    const unsigned hz1 = (iz + 1u) * 805459861u;

    const unsigned q00 = hy0 ^ hz0, q01 = hy0 ^ hz1;
    const unsigned q10 = hy1 ^ hz0, q11 = hy1 ^ hz1;

    const unsigned i00 = (ix ^ q00) & M;
    const unsigned i01 = (ix ^ q01) & M;
    const unsigned i10 = (ix ^ q10) & M;
    const unsigned i11 = (ix ^ q11) & M;

    const float4* __restrict__ tl4 = (const float4*)tl;
    const float4 f00 = tl4[i00 >> 1];
    const float4 f01 = tl4[i01 >> 1];
    const float4 f10 = tl4[i10 >> 1];
    const float4 f11 = tl4[i11 >> 1];

    const bool odd = (ix & 1u) != 0u;
    const unsigned jx = ix + 1u;
    float2 g00, g01, g10, g11;
    if (odd) {
        g00 = tl[(jx ^ q00) & M];
        g01 = tl[(jx ^ q01) & M];
        g10 = tl[(jx ^ q10) & M];
        g11 = tl[(jx ^ q11) & M];
    }

    const float2 lo00 = make_float2(f00.x, f00.y), hi00 = make_float2(f00.z, f00.w);
    const float2 lo01 = make_float2(f01.x, f01.y), hi01 = make_float2(f01.z, f01.w);
    const float2 lo10 = make_float2(f10.x, f10.y), hi10 = make_float2(f10.z, f10.w);
    const float2 lo11 = make_float2(f11.x, f11.y), hi11 = make_float2(f11.z, f11.w);

    const float2 c000 = (i00 & 1) ? hi00 : lo00;
    const float2 c001 = (i01 & 1) ? hi01 : lo01;
    const float2 c010 = (i10 & 1) ? hi10 : lo10;
    const float2 c011 = (i11 & 1) ? hi11 : lo11;
    const float2 c100 = odd ? g00 : ((i00 & 1) ? lo00 : hi00);
    const float2 c101 = odd ? g01 : ((i01 & 1) ? lo01 : hi01);
    const float2 c110 = odd ? g10 : ((i10 & 1) ? lo10 : hi10);
    const float2 c111 = odd ? g11 : ((i11 & 1) ? lo11 : hi11);

    const float ux = 1.f - wx, uy = 1.f - wy, uz = 1.f - wz;
    const float w000 = ux * uy * uz, w001 = ux * uy * wz;
    const float w010 = ux * wy * uz, w011 = ux * wy * wz;
    const float w100 = wx * uy * uz, w101 = wx * uy * wz;
    const float w110 = wx * wy * uz, w111 = wx * wy * wz;

    float ex = c000.x * w000 + c001.x * w001 + c010.x * w010 + c011.x * w011
             + c100.x * w100 + c101.x * w101 + c110.x * w110 + c111.x * w111;
    float ey = c000.y * w000 + c001.y * w001 + c010.y * w010 + c011.y * w011
             + c100.y * w100 + c101.y * w101 + c110.y * w110 + c111.y * w111;
    return make_float2(ex, ey);
}

// ---------- counting sort by (cluster | morton12) ----------

__global__ __launch_bounds__(BT) void k_zero(int* __restrict__ p) {
    const int i = blockIdx.x * BT + threadIdx.x;
    if (i < NBUCK) p[i] = 0;
}

__global__ __launch_bounds__(BT) void k_count(const float* __restrict__ pos,
                                              const float* __restrict__ cent,
                                              int* __restrict__ counts, int n) {
    const int gid = blockIdx.x * BT + threadIdx.x;
    if (gid < n) {
        float px = pos[gid * 3], py = pos[gid * 3 + 1], pz = pos[gid * 3 + 2];
        atomicAdd(&counts[sort_key(px, py, pz, cent)], 1);
    }
}

// single-block exclusive scan of NBUCK ints: 256 threads x 128 elems each
__global__ __launch_bounds__(BT) void k_scan(const int* __restrict__ counts,
                                             int* __restrict__ base,
                                             int* __restrict__ cursor) {
    __shared__ int part[BT];
    const int t = threadIdx.x;
    const int per = NBUCK / BT;   // 128
    int sum = 0;
    for (int i = 0; i < per; ++i) sum += counts[t * per + i];
    part[t] = sum;
    __syncthreads();
    // Hillis-Steele inclusive scan over 256 partials
    for (int off = 1; off < BT; off <<= 1) {
        int v = (t >= off) ? part[t - off] : 0;
        __syncthreads();
        part[t] += v;
        __syncthreads();
    }
    int run = (t == 0) ? 0 : part[t - 1];   // exclusive offset for this thread's chunk
    for (int i = 0; i < per; ++i) {
        const int idx = t * per + i;
        base[idx] = run;
        cursor[idx] = run;
        run += counts[idx];
    }
}

__global__ __launch_bounds__(BT) void k_scatter(const float* __restrict__ pos,
                                                const float* __restrict__ cent,
                                                int* __restrict__ cursor,
                                                float4* __restrict__ sorted, int n) {
    const int gid = blockIdx.x * BT + threadIdx.x;
    if (gid < n) {
        float px = pos[gid * 3], py = pos[gid * 3 + 1], pz = pos[gid * 3 + 2];
        const int key = sort_key(px, py, pz, cent);
        const int p = atomicAdd(&cursor[key], 1);
        sorted[p] = make_float4(px, py, pz, __int_as_float(gid));
    }
}

// ---------- fused gather+MLP over sorted points ----------

__global__ __launch_bounds__(BT) void k_main(const float4* __restrict__ sorted,
                                             const float2* __restrict__ tables,
                                             const float* __restrict__ cent,
                                             const float* __restrict__ W1,
                                             const float* __restrict__ b1,
                                             const float* __restrict__ W2,
                                             const float* __restrict__ b2,
                                             float* __restrict__ out, int n) {
    __shared__ float sW1[KF * W1S];
    __shared__ float sB1[KF * BS];
    __shared__ float sW2[KF * BS];
    __shared__ float sB2[KF];
    __shared__ float sC[KF * 3];

    const int tid = threadIdx.x;
    {
        const float4* __restrict__ W14 = (const float4*)W1;
        for (int idx = tid; idx < KF * INF * HID / 4; idx += BT) {
            int k = idx >> 8;
            int r = idx & 255;
            *(float4*)(sW1 + k * W1S + r * 4) = W14[idx];
        }
    }
    for (int idx = tid; idx < KF * HID; idx += BT) {
        int k = idx >> 6; int r = idx & 63;
        sB1[k * BS + r] = b1[idx];
        sW2[k * BS + r] = W2[idx];
    }
    if (tid < KF) sB2[tid] = b2[tid];
    if (tid < KF * 3) sC[tid] = cent[tid];
    __syncthreads();

    const int gid = blockIdx.x * BT + tid;
    if (gid >= n) return;

    const float4 p = sorted[gid];
    const int assign = cluster_assign(p.x, p.y, p.z, sC);

    float encr[INF];
    const float2* __restrict__ tab = tables + (size_t)assign * (LL * (size_t)TT);
    #pragma unroll
    for (int l = 0; l < LL; ++l) {
        float2 e = gather_level(tab + (size_t)l * TT, p.x, p.y, p.z, l);
        encr[l * 2 + 0] = e.x;
        encr[l * 2 + 1] = e.y;
    }

    const float4* __restrict__ w1k = (const float4*)(sW1 + assign * W1S);
    const float4* __restrict__ b1k = (const float4*)(sB1 + assign * BS);
    const float4* __restrict__ w2k = (const float4*)(sW2 + assign * BS);

    float outv = sB2[assign];
    #pragma unroll
    for (int j4 = 0; j4 < HID / 4; ++j4) {
        float4 a = b1k[j4];
        #pragma unroll
        for (int i = 0; i < INF; ++i) {
            const float4 w = w1k[i * (HID / 4) + j4];
            const float e = encr[i];
            a.x = fmaf(e, w.x, a.x);
            a.y = fmaf(e, w.y, a.y);
            a.z = fmaf(e, w.z, a.z);
            a.w = fmaf(e, w.w, a.w);
        }
        a.x = fmaxf(a.x, 0.f); a.y = fmaxf(a.y, 0.f);
        a.z = fmaxf(a.z, 0.f); a.w = fmaxf(a.w, 0.f);
        const float4 w2v = w2k[j4];
        outv = fmaf(a.x, w2v.x, outv);
        outv = fmaf(a.y, w2v.y, outv);
        outv = fmaf(a.z, w2v.z, outv);
        outv = fmaf(a.w, w2v.w, outv);
    }

    out[__float_as_int(p.w)] = expf(outv);
}

// ---------- fallback: unsorted fused (small ws) ----------

__global__ __launch_bounds__(BT) void k_fused(const float* __restrict__ positions,
                                              const float* __restrict__ centroids,
                                              const float* __restrict__ tables,
                                              const float* __restrict__ W1,
                                              const float* __restrict__ b1,
                                              const float* __restrict__ W2,
                                              const float* __restrict__ b2,
                                              float* __restrict__ out, int npts) {
    __shared__ float sW1[KF * W1S];
    __shared__ float sB1[KF * BS];
    __shared__ float sW2[KF * BS];
    __shared__ float sB2[KF];
    __shared__ float sC[KF * 3];

    const int tid = threadIdx.x;
    for (int idx = tid; idx < KF * INF * HID; idx += BT) {
        int k = idx >> 10; int r = idx & 1023;
        sW1[k * W1S + r] = W1[idx];
    }
    for (int idx = tid; idx < KF * HID; idx += BT) {
        int k = idx >> 6; int r = idx & 63;
        sB1[k * BS + r] = b1[idx];
        sW2[k * BS + r] = W2[idx];
    }
    if (tid < KF) sB2[tid] = b2[tid];
    if (tid < KF * 3) sC[tid] = centroids[tid];
    __syncthreads();

    const int gid = blockIdx.x * BT + tid;
    if (gid >= npts) return;

    const float px = positions[gid * 3 + 0];
    const float py = positions[gid * 3 + 1];
    const float pz = positions[gid * 3 + 2];
    const int assign = cluster_assign(px, py, pz, sC);

    float encr[INF];
    const float2* __restrict__ tab =
        (const float2*)tables + (size_t)assign * (LL * (size_t)TT);
    #pragma unroll
    for (int l = 0; l < LL; ++l) {
        float2 e = gather_level(tab + (size_t)l * TT, px, py, pz, l);
        encr[l * 2 + 0] = e.x;
        encr[l * 2 + 1] = e.y;
    }

    const float4* __restrict__ w1k = (const float4*)(sW1 + assign * W1S);
    const float4* __restrict__ b1k = (const float4*)(sB1 + assign * BS);
    const float4* __restrict__ w2k = (const float4*)(sW2 + assign * BS);

    float outv = sB2[assign];
    #pragma unroll
    for (int j4 = 0; j4 < HID / 4; ++j4) {
        float4 a = b1k[j4];
        #pragma unroll
        for (int i = 0; i < INF; ++i) {
            const float4 w = w1k[i * (HID / 4) + j4];
            const float e = encr[i];
            a.x = fmaf(e, w.x, a.x);
            a.y = fmaf(e, w.y, a.y);
            a.z = fmaf(e, w.z, a.z);
            a.w = fmaf(e, w.w, a.w);
        }
        a.x = fmaxf(a.x, 0.f); a.y = fmaxf(a.y, 0.f);
        a.z = fmaxf(a.z, 0.f); a.w = fmaxf(a.w, 0.f);
        const float4 w2v = w2k[j4];
        outv = fmaf(a.x, w2v.x, outv);
        outv = fmaf(a.y, w2v.y, outv);
        outv = fmaf(a.z, w2v.z, outv);
        outv = fmaf(a.w, w2v.w, outv);
    }
    out[gid] = expf(outv);
}

// ---------- launch ----------

extern "C" void kernel_launch(void* const* d_in, const int* in_sizes, int n_in,
                              void* d_out, int out_size, void* d_ws, size_t ws_size,
                              hipStream_t stream) {
    const float* positions = (const float*)d_in[0];
    const float* centroids = (const float*)d_in[1];
    const float* tables    = (const float*)d_in[2];
    const float* W1        = (const float*)d_in[3];
    const float* b1        = (const float*)d_in[4];
    const float* W2        = (const float*)d_in[5];
    const float* b2        = (const float*)d_in[6];
    float* out = (float*)d_out;

    const int n = in_sizes[0] / 3;
    const int nblk = (n + BT - 1) / BT;

    // ws layout: counts[NBUCK] | base[NBUCK] | cursor[NBUCK] | sorted float4[n]
    const size_t off_base   = (size_t)NBUCK * 4;
    const size_t off_cursor = (size_t)NBUCK * 8;
    const size_t off_sorted = (size_t)NBUCK * 12;
    const size_t need = off_sorted + (size_t)n * 16;

    if (ws_size >= need) {
        char* ws = (char*)d_ws;
        int* counts    = (int*)ws;
        int* base      = (int*)(ws + off_base);
        int* cursor    = (int*)(ws + off_cursor);
        float4* sorted = (float4*)(ws + off_sorted);

        k_zero<<<NBUCK / BT, BT, 0, stream>>>(counts);
        k_count<<<nblk, BT, 0, stream>>>(positions, centroids, counts, n);
        k_scan<<<1, BT, 0, stream>>>(counts, base, cursor);
        k_scatter<<<nblk, BT, 0, stream>>>(positions, centroids, cursor, sorted, n);
        k_main<<<nblk, BT, 0, stream>>>(sorted, (const float2*)tables, centroids,
                                        W1, b1, W2, b2, out, n);
    } else {
        k_fused<<<nblk, BT, 0, stream>>>(positions, centroids, tables,
                                         W1, b1, W2, b2, out, n);
    }
}